// Round 6
// baseline (1138.679 us; speedup 1.0000x reference)
//
#include <hip/hip_runtime.h>
#include <math.h>

// B=32, S=2048, D=512, R=4, H=32. Tokens = 65536. Tile = 64 tokens.
#define TOK 64

// Cross-half sum via the gfx950 permlane32_swap BUILTIN (SSA-safe; never use
// the inline-asm "+v","+v" form — R4 showed the allocator coalesces the two
// tied operands when they carry the same value -> self-swap). builtin returns
// {vdst_new, vsrc_new}; with both inputs = x this is {partner, own}, so
// r0+r1 == x + shfl_xor(x,32) bit-exactly (fp add commutes).
__device__ __forceinline__ float xhalf_sum(float a) {
    unsigned ai = __builtin_bit_cast(unsigned, a);
    auto r = __builtin_amdgcn_permlane32_swap(ai, ai, false, false);
    return __builtin_bit_cast(float, (unsigned)r[0]) +
           __builtin_bit_cast(float, (unsigned)r[1]);
}

// ---------------------------------------------------------------------------
// ONE fused kernel, 1056 blocks.
//   blocks 0..31    : GRU for batch b=blockIdx (dispatched FIRST so they grab
//                     CU slots and spin-acquire per-64-token flags).
//   blocks 32..1055 : producer q=blockIdx-32, tile = (q&31)*32 + (q>>5)
//                     (token-major: all batches' token-block k produced in
//                     wave k). Per tile: router -> write probs + release flag
//                     -> experts (reusing in-LDS probs).
// Producers never wait => deadlock-free regardless of dispatch order; GRU
// correctness depends only on acquire/release, not timing.
// ---------------------------------------------------------------------------
__global__ __launch_bounds__(256, 2) void k_fused(
    const float* __restrict__ x,
    const float* __restrict__ rw1, const float* __restrict__ rb1,
    const float* __restrict__ rw2, const float* __restrict__ rb2,
    const float* __restrict__ rw3, const float* __restrict__ rb3,
    const float* __restrict__ ew1, const float* __restrict__ eb1,
    const float* __restrict__ ew2, const float* __restrict__ eb2,
    const float* __restrict__ gwih, const float* __restrict__ gwhh,
    const float* __restrict__ gbih, const float* __restrict__ gbhh,
    float* __restrict__ probs_out, float* __restrict__ unc_out,
    float* __restrict__ weighted_out, float* __restrict__ trans_out,
    unsigned* __restrict__ flags)
{
    // LDS plan (~60.5 KB -> 2 blocks/CU):
    //   H1E1 : router H1 and experts E1 (same size, disjoint lifetimes)
    //   u    : router staging XsT+WsT, overlaid with router H2 (staging dead
    //          by the time layer2 writes H2; experts restage after L3)
    __shared__ float H1E1[64][132];
    union SU { struct { float XsT[32][68]; float WsT[32][132]; } s; float H2[64][68]; };
    __shared__ SU u;
    __shared__ float pS[64][4];
    __shared__ __align__(16) float hS[32];

    if (blockIdx.x < 32) {
        // ------------------------- GRU path -------------------------
        // One wave per batch. Lane l: j = l&31 (output index), half = l>>5
        // (K-half). EXACT R2/R5 fp accumulation order (the recurrence
        // amplifies per-step rounding ~5e3x — do NOT reorder). Same-wave DS
        // ops execute in order, so no explicit lgkmcnt drain is needed
        // between the hS write and the hk reads (compiler inserts the
        // register-dependency wait for the read data).
        if (threadIdx.x >= 64) return;
        const int b = blockIdx.x;
        const int l = threadIdx.x;
        const int j = l & 31, half = l >> 5;

        float whh[3][16];
#pragma unroll
        for (int g = 0; g < 3; g++) {
            const float* wp = gwhh + (j + 32 * g) * 32 + half * 16;
#pragma unroll
            for (int qq = 0; qq < 4; qq++) {
                float4 w = *(const float4*)(wp + qq * 4);
                whh[g][qq * 4 + 0] = w.x; whh[g][qq * 4 + 1] = w.y;
                whh[g][qq * 4 + 2] = w.z; whh[g][qq * 4 + 3] = w.w;
            }
        }
        float wih[3][4];
#pragma unroll
        for (int g = 0; g < 3; g++) {
            float4 w = *(const float4*)&gwih[(j + 32 * g) * 4];
            wih[g][0] = w.x; wih[g][1] = w.y; wih[g][2] = w.z; wih[g][3] = w.w;
        }
        const float bR = gbih[j] + gbhh[j];
        const float bZ = gbih[j + 32] + gbhh[j + 32];
        const float bIN = gbih[j + 64], bHN = gbhh[j + 64];

        float hk[16];
#pragma unroll
        for (int k = 0; k < 16; k++) hk[k] = 0.f;
        float hj = 0.f;
        float* tr = trans_out + (long)b * 2048 * 32 + j;
        const unsigned* flg = flags + b * 32;

        for (int blk = 0; blk < 32; ++blk) {
            // acquire this 64-token block's probs
            while (__hip_atomic_load(&flg[blk], __ATOMIC_ACQUIRE,
                                     __HIP_MEMORY_SCOPE_AGENT) == 0u) {
                __builtin_amdgcn_s_sleep(8);
            }
            const float* pt = probs_out + ((long)b * 2048 + blk * 64) * 4;
            float4 p0 = *(const float4*)pt;
            float4 p1 = *(const float4*)(pt + 4);

            for (int t = 0; t < 64; t++) {
                const int tn = (t + 2 < 64) ? (t + 2) : 63;   // stay in tile
                float4 p2 = *(const float4*)(pt + tn * 4);

                // partial matvec over this lane's K-half (48 fma, 6 chains)
                float aR0 = 0.f, aR1 = 0.f, aZ0 = 0.f, aZ1 = 0.f, aN0 = 0.f, aN1 = 0.f;
#pragma unroll
                for (int k = 0; k < 16; k += 2) {
                    aR0 = fmaf(whh[0][k],     hk[k],     aR0);
                    aR1 = fmaf(whh[0][k + 1], hk[k + 1], aR1);
                    aZ0 = fmaf(whh[1][k],     hk[k],     aZ0);
                    aZ1 = fmaf(whh[1][k + 1], hk[k + 1], aZ1);
                    aN0 = fmaf(whh[2][k],     hk[k],     aN0);
                    aN1 = fmaf(whh[2][k + 1], hk[k + 1], aN1);
                }
                float aR = xhalf_sum(aR0 + aR1);   // == aR + shfl_xor(aR,32)
                float aZ = xhalf_sum(aZ0 + aZ1);
                float aN = xhalf_sum(aN0 + aN1);

                // input-gate dots (independent of h -> overlaps swap latency)
                float giR = fmaf(wih[0][3], p0.w, fmaf(wih[0][2], p0.z,
                            fmaf(wih[0][1], p0.y, fmaf(wih[0][0], p0.x, bR))));
                float giZ = fmaf(wih[1][3], p0.w, fmaf(wih[1][2], p0.z,
                            fmaf(wih[1][1], p0.y, fmaf(wih[1][0], p0.x, bZ))));
                float giN = fmaf(wih[2][3], p0.w, fmaf(wih[2][2], p0.z,
                            fmaf(wih[2][1], p0.y, fmaf(wih[2][0], p0.x, bIN))));

                float r = __builtin_amdgcn_rcpf(1.f + __expf(-(giR + aR)));
                float z = __builtin_amdgcn_rcpf(1.f + __expf(-(giZ + aZ)));
                float nx = giN + r * (aN + bHN);
                float n = fmaf(2.f, __builtin_amdgcn_rcpf(1.f + __expf(-2.f * nx)), -1.f);
                hj = fmaf(z, hj - n, n);              // (1-z)*n + z*h

                if (l < 32) tr[(blk * 64 + t) * 32] = hj;
                hS[j] = hj;            // lanes j and j+32 write same value;
                                       // same-wave DS is in-order -> reads below see it
#pragma unroll
                for (int qq = 0; qq < 4; qq++) {
                    float4 h4 = *(const float4*)&hS[half * 16 + qq * 4];
                    hk[qq * 4 + 0] = h4.x; hk[qq * 4 + 1] = h4.y;
                    hk[qq * 4 + 2] = h4.z; hk[qq * 4 + 3] = h4.w;
                }
                p0 = p1; p1 = p2;
            }
        }
        return;
    }

    // ------------------------- producer path -------------------------
    const int q = blockIdx.x - 32;
    const int tile = (q & 31) * 32 + (q >> 5);   // b = q&31, token-block = q>>5
    const long t0 = (long)tile * TOK;

    const int tid = threadIdx.x;
    const int tx = tid & 15, ty = tid >> 4;

    // ============ ROUTER phase ============
    float acc[4][8];
#pragma unroll
    for (int i = 0; i < 4; i++)
#pragma unroll
        for (int o = 0; o < 8; o++) acc[i][o] = 0.f;

    for (int kc = 0; kc < 16; kc++) {
        __syncthreads();
#pragma unroll
        for (int s = 0; s < 2; s++) {
            int id = tid + s * 256;
            int tok = id >> 3, kq = id & 7;
            float4 v = *(const float4*)&x[(t0 + tok) * 512 + kc * 32 + kq * 4];
            u.s.XsT[kq * 4 + 0][tok] = v.x; u.s.XsT[kq * 4 + 1][tok] = v.y;
            u.s.XsT[kq * 4 + 2][tok] = v.z; u.s.XsT[kq * 4 + 3][tok] = v.w;
        }
#pragma unroll
        for (int s = 0; s < 4; s++) {
            int id = tid + s * 256;
            int out = id >> 3, kq = id & 7;
            float4 v = *(const float4*)&rw1[(long)out * 512 + kc * 32 + kq * 4];
            u.s.WsT[kq * 4 + 0][out] = v.x; u.s.WsT[kq * 4 + 1][out] = v.y;
            u.s.WsT[kq * 4 + 2][out] = v.z; u.s.WsT[kq * 4 + 3][out] = v.w;
        }
        __syncthreads();
#pragma unroll
        for (int k = 0; k < 32; k++) {
            const float4 xv = *(const float4*)&u.s.XsT[k][ty * 4];
            const float4 wa = *(const float4*)&u.s.WsT[k][tx * 4];
            const float4 wb = *(const float4*)&u.s.WsT[k][64 + tx * 4];
            const float xs[4] = {xv.x, xv.y, xv.z, xv.w};
            const float ws[8] = {wa.x, wa.y, wa.z, wa.w, wb.x, wb.y, wb.z, wb.w};
#pragma unroll
            for (int i = 0; i < 4; i++)
#pragma unroll
                for (int o = 0; o < 8; o++)
                    acc[i][o] = fmaf(xs[i], ws[o], acc[i][o]);
        }
    }

    // layer1 epilogue -> H1
#pragma unroll
    for (int o = 0; o < 8; o++) {
        const int col = (o < 4) ? (tx * 4 + o) : (64 + tx * 4 + (o - 4));
        float b = rb1[col];
#pragma unroll
        for (int i = 0; i < 4; i++) {
            float v = acc[i][o] + b;
            H1E1[ty * 4 + i][col] = v > 0.f ? v : 0.f;
        }
    }
    __syncthreads();   // H1 ready; u.s (staging) now dead -> H2 may overwrite

    // layer2 -> H2 (overlaid on staging region)
    float a2r[4][4];
#pragma unroll
    for (int i = 0; i < 4; i++)
#pragma unroll
        for (int o = 0; o < 4; o++) a2r[i][o] = 0.f;

    for (int k4 = 0; k4 < 32; k4++) {
        float4 hv[4], wv[4];
#pragma unroll
        for (int i = 0; i < 4; i++) hv[i] = *(const float4*)&H1E1[ty * 4 + i][k4 * 4];
#pragma unroll
        for (int o = 0; o < 4; o++) wv[o] = *(const float4*)&rw2[(tx * 4 + o) * 128 + k4 * 4];
#pragma unroll
        for (int i = 0; i < 4; i++)
#pragma unroll
            for (int o = 0; o < 4; o++)
                a2r[i][o] += hv[i].x * wv[o].x + hv[i].y * wv[o].y +
                             hv[i].z * wv[o].z + hv[i].w * wv[o].w;
    }
#pragma unroll
    for (int o = 0; o < 4; o++) {
        float b = rb2[tx * 4 + o];
#pragma unroll
        for (int i = 0; i < 4; i++) {
            float v = a2r[i][o] + b;
            u.H2[ty * 4 + i][tx * 4 + o] = v > 0.f ? v : 0.f;
        }
    }
    __syncthreads();

    // layer3 + softmax + std; probs -> global + pS (LDS)
    if (tid < 64) {
        int tok = tid;
        float lg[4];
#pragma unroll
        for (int r = 0; r < 4; r++) {
            float s = rb3[r];
            for (int k4 = 0; k4 < 16; k4++) {
                float4 h = *(const float4*)&u.H2[tok][k4 * 4];
                float4 w = *(const float4*)&rw3[r * 64 + k4 * 4];
                s += h.x * w.x + h.y * w.y + h.z * w.z + h.w * w.w;
            }
            lg[r] = s;
        }
        float m = fmaxf(fmaxf(lg[0], lg[1]), fmaxf(lg[2], lg[3]));
        float e0 = __expf(lg[0] - m), e1 = __expf(lg[1] - m);
        float e2 = __expf(lg[2] - m), e3 = __expf(lg[3] - m);
        float inv = __builtin_amdgcn_rcpf(e0 + e1 + e2 + e3);
        float p0 = e0 * inv, p1 = e1 * inv, p2 = e2 * inv, p3 = e3 * inv;
        *(float4*)&probs_out[(t0 + tok) * 4] = make_float4(p0, p1, p2, p3);
        pS[tok][0] = p0; pS[tok][1] = p1; pS[tok][2] = p2; pS[tok][3] = p3;
        float mean = 0.25f * (p0 + p1 + p2 + p3);
        float d0 = p0 - mean, d1 = p1 - mean, d2 = p2 - mean, d3 = p3 - mean;
        unc_out[t0 + tok] = sqrtf((d0 * d0 + d1 * d1 + d2 * d2 + d3 * d3) * (1.f / 3.f));
    }
    __syncthreads();   // probs stores complete (barrier drains mem ops)

    // publish this tile's probs to the GRU consumers
    if (tid == 0)
        __hip_atomic_store(&flags[tile], 1u, __ATOMIC_RELEASE,
                           __HIP_MEMORY_SCOPE_AGENT);

    // ============ EXPERTS phase ============
    float wacc[4][8];
#pragma unroll
    for (int i = 0; i < 4; i++)
#pragma unroll
        for (int o = 0; o < 8; o++) wacc[i][o] = 0.f;

    for (int g = 0; g < 2; g++) {   // regime pairs {0,1}, {2,3}
        float eacc[4][8];
#pragma unroll
        for (int i = 0; i < 4; i++)
#pragma unroll
            for (int o = 0; o < 8; o++) eacc[i][o] = 0.f;

        for (int kc = 0; kc < 16; kc++) {
            __syncthreads();
#pragma unroll
            for (int s = 0; s < 2; s++) {
                int id = tid + s * 256;
                int tok = id >> 3, kq = id & 7;
                float4 v = *(const float4*)&x[(t0 + tok) * 512 + kc * 32 + kq * 4];
                u.s.XsT[kq * 4 + 0][tok] = v.x; u.s.XsT[kq * 4 + 1][tok] = v.y;
                u.s.XsT[kq * 4 + 2][tok] = v.z; u.s.XsT[kq * 4 + 3][tok] = v.w;
            }
#pragma unroll
            for (int s = 0; s < 4; s++) {
                int id = tid + s * 256;
                int out = id >> 3, kq = id & 7;
                float4 v = *(const float4*)&ew1[(long)(g * 128 + out) * 512 + kc * 32 + kq * 4];
                u.s.WsT[kq * 4 + 0][out] = v.x; u.s.WsT[kq * 4 + 1][out] = v.y;
                u.s.WsT[kq * 4 + 2][out] = v.z; u.s.WsT[kq * 4 + 3][out] = v.w;
            }
            __syncthreads();
#pragma unroll
            for (int k = 0; k < 32; k++) {
                const float4 xv = *(const float4*)&u.s.XsT[k][ty * 4];
                const float4 wa = *(const float4*)&u.s.WsT[k][tx * 4];
                const float4 wb = *(const float4*)&u.s.WsT[k][64 + tx * 4];
                const float xs[4] = {xv.x, xv.y, xv.z, xv.w};
                const float ws[8] = {wa.x, wa.y, wa.z, wa.w, wb.x, wb.y, wb.z, wb.w};
#pragma unroll
                for (int i = 0; i < 4; i++)
#pragma unroll
                    for (int o = 0; o < 8; o++)
                        eacc[i][o] = fmaf(xs[i], ws[o], eacc[i][o]);
            }
        }
        __syncthreads();
        // e1 epilogue -> E1 (2 regimes of this pass)
#pragma unroll
        for (int o = 0; o < 8; o++) {
            const int col = (o < 4) ? (tx * 4 + o) : (64 + tx * 4 + (o - 4));
            float b = eb1[g * 128 + col];
#pragma unroll
            for (int i = 0; i < 4; i++) {
                float v = eacc[i][o] + b;
                H1E1[ty * 4 + i][col] = v > 0.f ? v : 0.f;
            }
        }
        __syncthreads();

        // layer2 per regime: K=64. Thread covers [4 tok][8 outs of 128].
        const int rl = tx >> 3;
        const int fb = (tx & 7) * 8;
        const int rg = g * 2 + rl;

        float a2[4][8];
#pragma unroll
        for (int i = 0; i < 4; i++)
#pragma unroll
            for (int o = 0; o < 8; o++) a2[i][o] = 0.f;

        for (int k4 = 0; k4 < 16; k4++) {
            float4 hv[4];
#pragma unroll
            for (int i = 0; i < 4; i++)
                hv[i] = *(const float4*)&H1E1[ty * 4 + i][rl * 64 + k4 * 4];
#pragma unroll
            for (int o = 0; o < 8; o++) {
                float4 wv = *(const float4*)&ew2[(long)(rg * 64 + fb + o) * 64 + k4 * 4];
#pragma unroll
                for (int i = 0; i < 4; i++)
                    a2[i][o] += hv[i].x * wv.x + hv[i].y * wv.y +
                                hv[i].z * wv.z + hv[i].w * wv.w;
            }
        }
        // weighted accumulate: wacc += p[tok][rg] * relu(a2 + eb2)
        float pr[4];
#pragma unroll
        for (int i = 0; i < 4; i++) pr[i] = pS[ty * 4 + i][rg];
#pragma unroll
        for (int o = 0; o < 8; o++) {
            float b = eb2[rg * 64 + fb + o];
#pragma unroll
            for (int i = 0; i < 4; i++) {
                float v = a2[i][o] + b;
                v = v > 0.f ? v : 0.f;
                wacc[i][o] = fmaf(pr[i], v, wacc[i][o]);
            }
        }
        __syncthreads();  // protect E1 before next pass overwrites
    }

    // reduce regimes across lane pairs (tx ^ 8) and store weighted
#pragma unroll
    for (int i = 0; i < 4; i++)
#pragma unroll
        for (int o = 0; o < 8; o++)
            wacc[i][o] += __shfl_xor(wacc[i][o], 8);

    if ((tx & 8) == 0) {
#pragma unroll
        for (int i = 0; i < 4; i++) {
            float4 v0 = make_float4(wacc[i][0], wacc[i][1], wacc[i][2], wacc[i][3]);
            float4 v1 = make_float4(wacc[i][4], wacc[i][5], wacc[i][6], wacc[i][7]);
            long base = (t0 + ty * 4 + i) * 64 + (tx & 7) * 8;
            *(float4*)&weighted_out[base] = v0;
            *(float4*)&weighted_out[base + 4] = v1;
        }
    }
}

extern "C" void kernel_launch(void* const* d_in, const int* in_sizes, int n_in,
                              void* d_out, int out_size, void* d_ws, size_t ws_size,
                              hipStream_t stream) {
    const float* x    = (const float*)d_in[0];
    const float* rw1  = (const float*)d_in[1];
    const float* rb1  = (const float*)d_in[2];
    const float* rw2  = (const float*)d_in[3];
    const float* rb2  = (const float*)d_in[4];
    const float* rw3  = (const float*)d_in[5];
    const float* rb3  = (const float*)d_in[6];
    const float* ew1  = (const float*)d_in[7];
    const float* eb1  = (const float*)d_in[8];
    const float* ew2  = (const float*)d_in[9];
    const float* eb2  = (const float*)d_in[10];
    const float* gwih = (const float*)d_in[11];
    const float* gwhh = (const float*)d_in[12];
    const float* gbih = (const float*)d_in[13];
    const float* gbhh = (const float*)d_in[14];

    float* out        = (float*)d_out;
    float* probs_o    = out;                         // 32*2048*4
    float* weighted_o = out + 262144;                // 32*2048*64
    float* trans_o    = out + 262144 + 4194304;      // 32*2048*32
    float* unc_o      = trans_o + 2097152;           // 32*2048

    unsigned* flags = (unsigned*)d_ws;               // 1024 tile flags
    hipMemsetAsync(d_ws, 0, 1024 * sizeof(unsigned), stream);

    hipLaunchKernelGGL(k_fused, dim3(1056), dim3(256), 0, stream,
                       x, rw1, rb1, rw2, rb2, rw3, rb3,
                       ew1, eb1, ew2, eb2,
                       gwih, gwhh, gbih, gbhh,
                       probs_o, unc_o, weighted_o, trans_o, flags);
}

// Round 7
// 1123.909 us; speedup vs baseline: 1.0131x; 1.0131x over previous
//
#include <hip/hip_runtime.h>
#include <math.h>

// B=32, S=2048, D=512, R=4, H=32. Tokens = 65536. Tile = 64 tokens.
#define TOK 64

// Cross-half sum via the gfx950 permlane32_swap BUILTIN (SSA-safe; never use
// the inline-asm "+v","+v" form — R4 showed the allocator coalesces the two
// tied operands when they carry the same value -> self-swap). builtin returns
// {vdst_new, vsrc_new}; with both inputs = x this is {partner, own}, so
// r0+r1 == x + shfl_xor(x,32) bit-exactly (fp add commutes).
__device__ __forceinline__ float xhalf_sum(float a) {
    unsigned ai = __builtin_bit_cast(unsigned, a);
    auto r = __builtin_amdgcn_permlane32_swap(ai, ai, false, false);
    return __builtin_bit_cast(float, (unsigned)r[0]) +
           __builtin_bit_cast(float, (unsigned)r[1]);
}

// ---------------------------------------------------------------------------
// ONE fused kernel, 1056 blocks.
//   blocks 0..31    : GRU for batch b=blockIdx (dispatched FIRST so they grab
//                     CU slots and spin-acquire per-64-token flags).
//   blocks 32..1055 : producer q=blockIdx-32, tile = (q&31)*32 + (q>>5)
//                     (token-major: all batches' token-block k produced in
//                     wave k). Per tile: router -> write probs + release flag
//                     -> experts (reusing in-LDS probs).
// Spin-wait uses RELAXED agent-scope loads (coherent read-through, NO cache
// invalidation) + ONE acquire fence after the flag is seen. R6's per-poll
// ACQUIRE loads caused an L2-invalidate storm that latency-stretched the
// whole chip (FETCH +75MB, dur 1283us).
// ---------------------------------------------------------------------------
__global__ __launch_bounds__(256, 2) void k_fused(
    const float* __restrict__ x,
    const float* __restrict__ rw1, const float* __restrict__ rb1,
    const float* __restrict__ rw2, const float* __restrict__ rb2,
    const float* __restrict__ rw3, const float* __restrict__ rb3,
    const float* __restrict__ ew1, const float* __restrict__ eb1,
    const float* __restrict__ ew2, const float* __restrict__ eb2,
    const float* __restrict__ gwih, const float* __restrict__ gwhh,
    const float* __restrict__ gbih, const float* __restrict__ gbhh,
    float* __restrict__ probs_out, float* __restrict__ unc_out,
    float* __restrict__ weighted_out, float* __restrict__ trans_out,
    unsigned* __restrict__ flags)
{
    // LDS plan (~60.5 KB -> 2 blocks/CU):
    //   H1E1 : router H1 and experts E1 (same size, disjoint lifetimes)
    //   u    : router staging XsT+WsT, overlaid with router H2 (staging dead
    //          by the time layer2 writes H2; experts restage after L3)
    __shared__ float H1E1[64][132];
    union SU { struct { float XsT[32][68]; float WsT[32][132]; } s; float H2[64][68]; };
    __shared__ SU u;
    __shared__ float pS[64][4];
    __shared__ __align__(16) float hS[32];

    if (blockIdx.x < 32) {
        // ------------------------- GRU path -------------------------
        // One wave per batch. Lane l: j = l&31 (output index), half = l>>5
        // (K-half). EXACT R2/R5 fp accumulation order (the recurrence
        // amplifies per-step rounding ~5e3x — do NOT reorder). Same-wave DS
        // ops execute in order, so no explicit lgkmcnt drain is needed
        // between the hS write and the hk reads.
        if (threadIdx.x >= 64) return;
        const int b = blockIdx.x;
        const int l = threadIdx.x;
        const int j = l & 31, half = l >> 5;

        float whh[3][16];
#pragma unroll
        for (int g = 0; g < 3; g++) {
            const float* wp = gwhh + (j + 32 * g) * 32 + half * 16;
#pragma unroll
            for (int qq = 0; qq < 4; qq++) {
                float4 w = *(const float4*)(wp + qq * 4);
                whh[g][qq * 4 + 0] = w.x; whh[g][qq * 4 + 1] = w.y;
                whh[g][qq * 4 + 2] = w.z; whh[g][qq * 4 + 3] = w.w;
            }
        }
        float wih[3][4];
#pragma unroll
        for (int g = 0; g < 3; g++) {
            float4 w = *(const float4*)&gwih[(j + 32 * g) * 4];
            wih[g][0] = w.x; wih[g][1] = w.y; wih[g][2] = w.z; wih[g][3] = w.w;
        }
        const float bR = gbih[j] + gbhh[j];
        const float bZ = gbih[j + 32] + gbhh[j + 32];
        const float bIN = gbih[j + 64], bHN = gbhh[j + 64];

        float hk[16];
#pragma unroll
        for (int k = 0; k < 16; k++) hk[k] = 0.f;
        float hj = 0.f;
        float* tr = trans_out + (long)b * 2048 * 32 + j;
        const unsigned* flg = flags + b * 32;

        for (int blk = 0; blk < 32; ++blk) {
            // poll with RELAXED coherent loads (no invalidation)...
            while (__hip_atomic_load(&flg[blk], __ATOMIC_RELAXED,
                                     __HIP_MEMORY_SCOPE_AGENT) == 0u) {
                __builtin_amdgcn_s_sleep(16);
            }
            // ...then ONE acquire fence before reading the published probs
            __builtin_amdgcn_fence(__ATOMIC_ACQUIRE, "agent");

            const float* pt = probs_out + ((long)b * 2048 + blk * 64) * 4;
            float4 p0 = *(const float4*)pt;
            float4 p1 = *(const float4*)(pt + 4);

            for (int t = 0; t < 64; t++) {
                const int tn = (t + 2 < 64) ? (t + 2) : 63;   // stay in tile
                float4 p2 = *(const float4*)(pt + tn * 4);

                // partial matvec over this lane's K-half (48 fma, 6 chains)
                float aR0 = 0.f, aR1 = 0.f, aZ0 = 0.f, aZ1 = 0.f, aN0 = 0.f, aN1 = 0.f;
#pragma unroll
                for (int k = 0; k < 16; k += 2) {
                    aR0 = fmaf(whh[0][k],     hk[k],     aR0);
                    aR1 = fmaf(whh[0][k + 1], hk[k + 1], aR1);
                    aZ0 = fmaf(whh[1][k],     hk[k],     aZ0);
                    aZ1 = fmaf(whh[1][k + 1], hk[k + 1], aZ1);
                    aN0 = fmaf(whh[2][k],     hk[k],     aN0);
                    aN1 = fmaf(whh[2][k + 1], hk[k + 1], aN1);
                }
                float aR = xhalf_sum(aR0 + aR1);   // == aR + shfl_xor(aR,32)
                float aZ = xhalf_sum(aZ0 + aZ1);
                float aN = xhalf_sum(aN0 + aN1);

                // input-gate dots (independent of h -> overlaps swap latency)
                float giR = fmaf(wih[0][3], p0.w, fmaf(wih[0][2], p0.z,
                            fmaf(wih[0][1], p0.y, fmaf(wih[0][0], p0.x, bR))));
                float giZ = fmaf(wih[1][3], p0.w, fmaf(wih[1][2], p0.z,
                            fmaf(wih[1][1], p0.y, fmaf(wih[1][0], p0.x, bZ))));
                float giN = fmaf(wih[2][3], p0.w, fmaf(wih[2][2], p0.z,
                            fmaf(wih[2][1], p0.y, fmaf(wih[2][0], p0.x, bIN))));

                float r = __builtin_amdgcn_rcpf(1.f + __expf(-(giR + aR)));
                float z = __builtin_amdgcn_rcpf(1.f + __expf(-(giZ + aZ)));
                float nx = giN + r * (aN + bHN);
                float n = fmaf(2.f, __builtin_amdgcn_rcpf(1.f + __expf(-2.f * nx)), -1.f);
                hj = fmaf(z, hj - n, n);              // (1-z)*n + z*h

                if (l < 32) tr[(blk * 64 + t) * 32] = hj;
                hS[j] = hj;            // lanes j and j+32 write same value;
                                       // same-wave DS is in-order
#pragma unroll
                for (int qq = 0; qq < 4; qq++) {
                    float4 h4 = *(const float4*)&hS[half * 16 + qq * 4];
                    hk[qq * 4 + 0] = h4.x; hk[qq * 4 + 1] = h4.y;
                    hk[qq * 4 + 2] = h4.z; hk[qq * 4 + 3] = h4.w;
                }
                p0 = p1; p1 = p2;
            }
        }
        return;
    }

    // ------------------------- producer path -------------------------
    const int q = blockIdx.x - 32;
    const int tile = (q & 31) * 32 + (q >> 5);   // b = q&31, token-block = q>>5
    const long t0 = (long)tile * TOK;

    const int tid = threadIdx.x;
    const int tx = tid & 15, ty = tid >> 4;

    // ============ ROUTER phase ============
    float acc[4][8];
#pragma unroll
    for (int i = 0; i < 4; i++)
#pragma unroll
        for (int o = 0; o < 8; o++) acc[i][o] = 0.f;

    for (int kc = 0; kc < 16; kc++) {
        __syncthreads();
#pragma unroll
        for (int s = 0; s < 2; s++) {
            int id = tid + s * 256;
            int tok = id >> 3, kq = id & 7;
            float4 v = *(const float4*)&x[(t0 + tok) * 512 + kc * 32 + kq * 4];
            u.s.XsT[kq * 4 + 0][tok] = v.x; u.s.XsT[kq * 4 + 1][tok] = v.y;
            u.s.XsT[kq * 4 + 2][tok] = v.z; u.s.XsT[kq * 4 + 3][tok] = v.w;
        }
#pragma unroll
        for (int s = 0; s < 4; s++) {
            int id = tid + s * 256;
            int out = id >> 3, kq = id & 7;
            float4 v = *(const float4*)&rw1[(long)out * 512 + kc * 32 + kq * 4];
            u.s.WsT[kq * 4 + 0][out] = v.x; u.s.WsT[kq * 4 + 1][out] = v.y;
            u.s.WsT[kq * 4 + 2][out] = v.z; u.s.WsT[kq * 4 + 3][out] = v.w;
        }
        __syncthreads();
#pragma unroll
        for (int k = 0; k < 32; k++) {
            const float4 xv = *(const float4*)&u.s.XsT[k][ty * 4];
            const float4 wa = *(const float4*)&u.s.WsT[k][tx * 4];
            const float4 wb = *(const float4*)&u.s.WsT[k][64 + tx * 4];
            const float xs[4] = {xv.x, xv.y, xv.z, xv.w};
            const float ws[8] = {wa.x, wa.y, wa.z, wa.w, wb.x, wb.y, wb.z, wb.w};
#pragma unroll
            for (int i = 0; i < 4; i++)
#pragma unroll
                for (int o = 0; o < 8; o++)
                    acc[i][o] = fmaf(xs[i], ws[o], acc[i][o]);
        }
    }

    // layer1 epilogue -> H1
#pragma unroll
    for (int o = 0; o < 8; o++) {
        const int col = (o < 4) ? (tx * 4 + o) : (64 + tx * 4 + (o - 4));
        float b = rb1[col];
#pragma unroll
        for (int i = 0; i < 4; i++) {
            float v = acc[i][o] + b;
            H1E1[ty * 4 + i][col] = v > 0.f ? v : 0.f;
        }
    }
    __syncthreads();   // H1 ready; u.s (staging) now dead -> H2 may overwrite

    // layer2 -> H2 (overlaid on staging region)
    float a2r[4][4];
#pragma unroll
    for (int i = 0; i < 4; i++)
#pragma unroll
        for (int o = 0; o < 4; o++) a2r[i][o] = 0.f;

    for (int k4 = 0; k4 < 32; k4++) {
        float4 hv[4], wv[4];
#pragma unroll
        for (int i = 0; i < 4; i++) hv[i] = *(const float4*)&H1E1[ty * 4 + i][k4 * 4];
#pragma unroll
        for (int o = 0; o < 4; o++) wv[o] = *(const float4*)&rw2[(tx * 4 + o) * 128 + k4 * 4];
#pragma unroll
        for (int i = 0; i < 4; i++)
#pragma unroll
            for (int o = 0; o < 4; o++)
                a2r[i][o] += hv[i].x * wv[o].x + hv[i].y * wv[o].y +
                             hv[i].z * wv[o].z + hv[i].w * wv[o].w;
    }
#pragma unroll
    for (int o = 0; o < 4; o++) {
        float b = rb2[tx * 4 + o];
#pragma unroll
        for (int i = 0; i < 4; i++) {
            float v = a2r[i][o] + b;
            u.H2[ty * 4 + i][tx * 4 + o] = v > 0.f ? v : 0.f;
        }
    }
    __syncthreads();

    // layer3 + softmax + std; probs -> global + pS (LDS)
    if (tid < 64) {
        int tok = tid;
        float lg[4];
#pragma unroll
        for (int r = 0; r < 4; r++) {
            float s = rb3[r];
            for (int k4 = 0; k4 < 16; k4++) {
                float4 h = *(const float4*)&u.H2[tok][k4 * 4];
                float4 w = *(const float4*)&rw3[r * 64 + k4 * 4];
                s += h.x * w.x + h.y * w.y + h.z * w.z + h.w * w.w;
            }
            lg[r] = s;
        }
        float m = fmaxf(fmaxf(lg[0], lg[1]), fmaxf(lg[2], lg[3]));
        float e0 = __expf(lg[0] - m), e1 = __expf(lg[1] - m);
        float e2 = __expf(lg[2] - m), e3 = __expf(lg[3] - m);
        float inv = __builtin_amdgcn_rcpf(e0 + e1 + e2 + e3);
        float p0 = e0 * inv, p1 = e1 * inv, p2 = e2 * inv, p3 = e3 * inv;
        *(float4*)&probs_out[(t0 + tok) * 4] = make_float4(p0, p1, p2, p3);
        pS[tok][0] = p0; pS[tok][1] = p1; pS[tok][2] = p2; pS[tok][3] = p3;
        float mean = 0.25f * (p0 + p1 + p2 + p3);
        float d0 = p0 - mean, d1 = p1 - mean, d2 = p2 - mean, d3 = p3 - mean;
        unc_out[t0 + tok] = sqrtf((d0 * d0 + d1 * d1 + d2 * d2 + d3 * d3) * (1.f / 3.f));
    }
    __syncthreads();   // probs stores issued by all lanes before release

    // publish this tile's probs to the GRU consumers
    if (tid == 0)
        __hip_atomic_store(&flags[tile], 1u, __ATOMIC_RELEASE,
                           __HIP_MEMORY_SCOPE_AGENT);

    // ============ EXPERTS phase ============
    float wacc[4][8];
#pragma unroll
    for (int i = 0; i < 4; i++)
#pragma unroll
        for (int o = 0; o < 8; o++) wacc[i][o] = 0.f;

    for (int g = 0; g < 2; g++) {   // regime pairs {0,1}, {2,3}
        float eacc[4][8];
#pragma unroll
        for (int i = 0; i < 4; i++)
#pragma unroll
            for (int o = 0; o < 8; o++) eacc[i][o] = 0.f;

        for (int kc = 0; kc < 16; kc++) {
            __syncthreads();
#pragma unroll
            for (int s = 0; s < 2; s++) {
                int id = tid + s * 256;
                int tok = id >> 3, kq = id & 7;
                float4 v = *(const float4*)&x[(t0 + tok) * 512 + kc * 32 + kq * 4];
                u.s.XsT[kq * 4 + 0][tok] = v.x; u.s.XsT[kq * 4 + 1][tok] = v.y;
                u.s.XsT[kq * 4 + 2][tok] = v.z; u.s.XsT[kq * 4 + 3][tok] = v.w;
            }
#pragma unroll
            for (int s = 0; s < 4; s++) {
                int id = tid + s * 256;
                int out = id >> 3, kq = id & 7;
                float4 v = *(const float4*)&ew1[(long)(g * 128 + out) * 512 + kc * 32 + kq * 4];
                u.s.WsT[kq * 4 + 0][out] = v.x; u.s.WsT[kq * 4 + 1][out] = v.y;
                u.s.WsT[kq * 4 + 2][out] = v.z; u.s.WsT[kq * 4 + 3][out] = v.w;
            }
            __syncthreads();
#pragma unroll
            for (int k = 0; k < 32; k++) {
                const float4 xv = *(const float4*)&u.s.XsT[k][ty * 4];
                const float4 wa = *(const float4*)&u.s.WsT[k][tx * 4];
                const float4 wb = *(const float4*)&u.s.WsT[k][64 + tx * 4];
                const float xs[4] = {xv.x, xv.y, xv.z, xv.w};
                const float ws[8] = {wa.x, wa.y, wa.z, wa.w, wb.x, wb.y, wb.z, wb.w};
#pragma unroll
                for (int i = 0; i < 4; i++)
#pragma unroll
                    for (int o = 0; o < 8; o++)
                        eacc[i][o] = fmaf(xs[i], ws[o], eacc[i][o]);
            }
        }
        __syncthreads();
        // e1 epilogue -> E1 (2 regimes of this pass)
#pragma unroll
        for (int o = 0; o < 8; o++) {
            const int col = (o < 4) ? (tx * 4 + o) : (64 + tx * 4 + (o - 4));
            float b = eb1[g * 128 + col];
#pragma unroll
            for (int i = 0; i < 4; i++) {
                float v = eacc[i][o] + b;
                H1E1[ty * 4 + i][col] = v > 0.f ? v : 0.f;
            }
        }
        __syncthreads();

        // layer2 per regime: K=64. Thread covers [4 tok][8 outs of 128].
        const int rl = tx >> 3;
        const int fb = (tx & 7) * 8;
        const int rg = g * 2 + rl;

        float a2[4][8];
#pragma unroll
        for (int i = 0; i < 4; i++)
#pragma unroll
            for (int o = 0; o < 8; o++) a2[i][o] = 0.f;

        for (int k4 = 0; k4 < 16; k4++) {
            float4 hv[4];
#pragma unroll
            for (int i = 0; i < 4; i++)
                hv[i] = *(const float4*)&H1E1[ty * 4 + i][rl * 64 + k4 * 4];
#pragma unroll
            for (int o = 0; o < 8; o++) {
                float4 wv = *(const float4*)&ew2[(long)(rg * 64 + fb + o) * 64 + k4 * 4];
#pragma unroll
                for (int i = 0; i < 4; i++)
                    a2[i][o] += hv[i].x * wv.x + hv[i].y * wv.y +
                                hv[i].z * wv.z + hv[i].w * wv.w;
            }
        }
        // weighted accumulate: wacc += p[tok][rg] * relu(a2 + eb2)
        float pr[4];
#pragma unroll
        for (int i = 0; i < 4; i++) pr[i] = pS[ty * 4 + i][rg];
#pragma unroll
        for (int o = 0; o < 8; o++) {
            float b = eb2[rg * 64 + fb + o];
#pragma unroll
            for (int i = 0; i < 4; i++) {
                float v = a2[i][o] + b;
                v = v > 0.f ? v : 0.f;
                wacc[i][o] = fmaf(pr[i], v, wacc[i][o]);
            }
        }
        __syncthreads();  // protect E1 before next pass overwrites
    }

    // reduce regimes across lane pairs (tx ^ 8) and store weighted
#pragma unroll
    for (int i = 0; i < 4; i++)
#pragma unroll
        for (int o = 0; o < 8; o++)
            wacc[i][o] += __shfl_xor(wacc[i][o], 8);

    if ((tx & 8) == 0) {
#pragma unroll
        for (int i = 0; i < 4; i++) {
            float4 v0 = make_float4(wacc[i][0], wacc[i][1], wacc[i][2], wacc[i][3]);
            float4 v1 = make_float4(wacc[i][4], wacc[i][5], wacc[i][6], wacc[i][7]);
            long base = (t0 + ty * 4 + i) * 64 + (tx & 7) * 8;
            *(float4*)&weighted_out[base] = v0;
            *(float4*)&weighted_out[base + 4] = v1;
        }
    }
}

extern "C" void kernel_launch(void* const* d_in, const int* in_sizes, int n_in,
                              void* d_out, int out_size, void* d_ws, size_t ws_size,
                              hipStream_t stream) {
    const float* x    = (const float*)d_in[0];
    const float* rw1  = (const float*)d_in[1];
    const float* rb1  = (const float*)d_in[2];
    const float* rw2  = (const float*)d_in[3];
    const float* rb2  = (const float*)d_in[4];
    const float* rw3  = (const float*)d_in[5];
    const float* rb3  = (const float*)d_in[6];
    const float* ew1  = (const float*)d_in[7];
    const float* eb1  = (const float*)d_in[8];
    const float* ew2  = (const float*)d_in[9];
    const float* eb2  = (const float*)d_in[10];
    const float* gwih = (const float*)d_in[11];
    const float* gwhh = (const float*)d_in[12];
    const float* gbih = (const float*)d_in[13];
    const float* gbhh = (const float*)d_in[14];

    float* out        = (float*)d_out;
    float* probs_o    = out;                         // 32*2048*4
    float* weighted_o = out + 262144;                // 32*2048*64
    float* trans_o    = out + 262144 + 4194304;      // 32*2048*32
    float* unc_o      = trans_o + 2097152;           // 32*2048

    unsigned* flags = (unsigned*)d_ws;               // 1024 tile flags
    hipMemsetAsync(d_ws, 0, 1024 * sizeof(unsigned), stream);

    hipLaunchKernelGGL(k_fused, dim3(1056), dim3(256), 0, stream,
                       x, rw1, rb1, rw2, rb2, rw3, rb3,
                       ew1, eb1, ew2, eb2,
                       gwih, gwhh, gbih, gbhh,
                       probs_o, unc_o, weighted_o, trans_o, flags);
}